// Round 3
// baseline (131.724 us; speedup 1.0000x reference)
//
#include <hip/hip_runtime.h>
#include <math.h>

#define F 128
#define HID 32
#define NH 4
#define CHUNK 256

__device__ __forceinline__ float silu_f(float x) {
    return x / (1.0f + __expf(-x));
}

// Scatter segment boundaries: starts[b] = first atom index with seg_id >= b.
__global__ void seg_starts_kernel(const int* __restrict__ seg, int* __restrict__ starts,
                                  int N, int B) {
    int i = blockIdx.x * blockDim.x + threadIdx.x;
    if (i >= N) return;
    int id = seg[i];
    if (i == 0) {
        for (int b = 0; b <= id; ++b) starts[b] = 0;
    } else {
        int prev = seg[i - 1];
        for (int b = prev + 1; b <= id; ++b) starts[b] = i;
    }
    if (i == N - 1) {
        for (int b = id + 1; b <= B; ++b) starts[b] = N;
    }
}

// Fused: key-MLP (lane-per-atom, W1/W2 uniform scalar loads) + exact chunked
// online segment softmax (wave-per-head) + weighted feature sum + output proj.
// One block per crystal, 256 threads.
__global__ __launch_bounds__(256, 4) void fused_readout_kernel(
    const float* __restrict__ atom_fea, const int* __restrict__ starts,
    const float* __restrict__ W1, const float* __restrict__ b1,
    const float* __restrict__ W2, const float* __restrict__ b2,
    const float* __restrict__ Wp, const float* __restrict__ bp,
    float* __restrict__ out) {
    __shared__ float sTL[CHUNK * NH];  // chunk logits [slot][head], 4 KB
    __shared__ float sTW[CHUNK * NH];  // chunk exp-weights, 4 KB

    const int t = threadIdx.x;
    const int b = blockIdx.x;
    const int start = starts[b];
    const int end = starts[b + 1];
    const int head = t >> 6;      // wave id == head owned in softmax/accumulate
    const int lane = t & 63;
    const int f0 = lane * 2;      // feature pair owned in accumulate

    float m_run = -INFINITY;
    float s_run = 0.0f;
    float acc0 = 0.0f, acc1 = 0.0f;

    for (int base = start; base < end; base += CHUNK) {
        const int T = min(CHUNK, end - base);

        // ---- phase A: lane-per-atom key MLP (global row stream, scalar W1) ----
        float4 p4 = make_float4(-INFINITY, -INFINITY, -INFINITY, -INFINITY);
        if (t < T) {
            const int a = base + t;
            float acc[HID];
            #pragma unroll
            for (int h = 0; h < HID; ++h) acc[h] = b1[h];
            const float* row = atom_fea + (size_t)a * F;
            for (int c = 0; c < 4; ++c) {
                float fr[32];
                #pragma unroll
                for (int q = 0; q < 8; ++q)
                    *(float4*)&fr[q * 4] = *(const float4*)&row[c * 32 + q * 4];
                #pragma unroll
                for (int k = 0; k < 32; ++k) {
                    const float fk = fr[k];
                    const float* w1r = &W1[(c * 32 + k) * HID];  // uniform -> s_load
                    #pragma unroll
                    for (int h = 0; h < HID; ++h) acc[h] = fmaf(fk, w1r[h], acc[h]);
                }
            }
            float p[NH] = {b2[0], b2[1], b2[2], b2[3]};
            #pragma unroll
            for (int h = 0; h < HID; ++h) {
                const float sv = silu_f(acc[h]);
                #pragma unroll
                for (int j = 0; j < NH; ++j) p[j] = fmaf(sv, W2[h * NH + j], p[j]);
            }
            p4 = make_float4(p[0], p[1], p[2], p[3]);
        }
        *(float4*)&sTL[t * NH] = p4;
        __syncthreads();

        // ---- phase B: wave `head` online softmax over this chunk ----
        float mt = -INFINITY;
        #pragma unroll
        for (int q = 0; q < 4; ++q) mt = fmaxf(mt, sTL[(lane + q * 64) * NH + head]);
        #pragma unroll
        for (int d = 1; d < 64; d <<= 1) mt = fmaxf(mt, __shfl_xor(mt, d));
        const float m_new = fmaxf(m_run, mt);
        const float r = __expf(m_run - m_new);  // first chunk: exp(-inf)=0
        float se = 0.0f;
        #pragma unroll
        for (int q = 0; q < 4; ++q) {
            const int s = lane + q * 64;
            const float e = __expf(sTL[s * NH + head] - m_new);  // invalid slots -> 0
            sTW[s * NH + head] = e;
            se += e;
        }
        #pragma unroll
        for (int d = 1; d < 64; d <<= 1) se += __shfl_xor(se, d);
        s_run = fmaf(s_run, r, se);
        m_run = m_new;
        acc0 *= r;
        acc1 *= r;
        // own wave wrote own head's sTW column -> no barrier before phase C

        // ---- phase C: weighted accumulate, rows re-read coalesced (cache-hot) ----
        const float* rowbase = atom_fea + (size_t)base * F + f0;
        #pragma unroll 4
        for (int a2 = 0; a2 < T; ++a2) {
            const float w = sTW[a2 * NH + head];  // wave-broadcast
            const float2 v = *(const float2*)(rowbase + (size_t)a2 * F);
            acc0 = fmaf(w, v.x, acc0);
            acc1 = fmaf(w, v.y, acc1);
        }
        __syncthreads();  // protect sTL/sTW before next chunk
    }

    const float inv = (s_run > 0.0f) ? 1.0f / s_run : 0.0f;

    // ---- epilogue: out[b] = silu(wacc @ Wp + bp), reuse LDS ----
    float* sWacc = sTL;  // 512 floats, k = h*F + f
    float* sPart = sTW;  // 256 floats
    sWacc[head * F + f0] = acc0 * inv;
    sWacc[head * F + f0 + 1] = acc1 * inv;
    __syncthreads();
    {
        const int f = t & 127, half = t >> 7;
        float sum = 0.0f;
        const float* wp = Wp + (size_t)(half * 256) * F + f;
        const float* wa = &sWacc[half * 256];
        #pragma unroll 8
        for (int k = 0; k < 256; ++k) sum = fmaf(wa[k], wp[(size_t)k * F], sum);
        sPart[t] = sum;
    }
    __syncthreads();
    if (t < 128) out[(size_t)b * F + t] = silu_f(sPart[t] + sPart[t + 128] + bp[t]);
}

extern "C" void kernel_launch(void* const* d_in, const int* in_sizes, int n_in,
                              void* d_out, int out_size, void* d_ws, size_t ws_size,
                              hipStream_t stream) {
    const float* atom_fea = (const float*)d_in[0];
    const int* seg = (const int*)d_in[1];
    const float* W1 = (const float*)d_in[3];
    const float* b1 = (const float*)d_in[4];
    const float* W2 = (const float*)d_in[5];
    const float* b2 = (const float*)d_in[6];
    const float* Wp = (const float*)d_in[7];
    const float* bp = (const float*)d_in[8];
    float* out = (float*)d_out;

    const int N = in_sizes[0] / F;
    const int B = out_size / F;
    int* starts = (int*)d_ws;  // (B+1) ints

    seg_starts_kernel<<<(N + 255) / 256, 256, 0, stream>>>(seg, starts, N, B);
    fused_readout_kernel<<<B, 256, 0, stream>>>(atom_fea, starts, W1, b1, W2, b2, Wp, bp, out);
}